// Round 8
// baseline (442.714 us; speedup 1.0000x reference)
//
#include <hip/hip_runtime.h>

// Problem constants: B=8, M=N=256, D=512
#define INFV 1.0e8f
#define NB 2            // batches interleaved per wave (cell-level ILP)

// Raw HW transcendentals: v_exp_f32 is 2^x, v_log_f32 is log2(x).
#define EXP2F(x) __builtin_amdgcn_exp2f(x)
#define LOG2F(x) __builtin_amdgcn_logf(x)

// Block-diagonal layout: 4x4 cell blocks (I,J), I,J in [0,64).
// chunk s = I+J; tensor[b][s][I][16], idx-in-block = j*4+k
// (j = col 0..3, k = row 0..3).  Chunk = 1024 floats; 128 chunks/batch.
#define CHUNK 1024
#define BSTRIDE 131072   // floats per batch per tensor

__device__ __forceinline__ void ld4(float d[4], const float* p) {
  float4 v = *(const float4*)p;
  d[0] = v.x; d[1] = v.y; d[2] = v.z; d[3] = v.w;
}
__device__ __forceinline__ void ld16(float d[16], const float* p) {
  ld4(d, p); ld4(d + 4, p + 4); ld4(d + 8, p + 8); ld4(d + 12, p + 12);
}

// ---------------------------------------------------------------------------
// Kernel 1: inverse row norms.  rn = 1 / max(||row||, 1e-8)
// ---------------------------------------------------------------------------
__global__ void __launch_bounds__(256) norms_kernel(const float* __restrict__ x,
                                                    const float* __restrict__ y,
                                                    float* __restrict__ rnx,
                                                    float* __restrict__ rny) {
  int g = blockIdx.x * 4 + (threadIdx.x >> 6);
  int lane = threadIdx.x & 63;
  const float* src; float* dst; int row;
  if (g < 2048) { src = x; dst = rnx; row = g; }
  else          { src = y; dst = rny; row = g - 2048; }
  const float* p = src + (size_t)row * 512;
  float4 v0 = *(const float4*)(p + lane * 4);
  float4 v1 = *(const float4*)(p + 256 + lane * 4);
  float s = v0.x*v0.x + v0.y*v0.y + v0.z*v0.z + v0.w*v0.w
          + v1.x*v1.x + v1.y*v1.y + v1.z*v1.z + v1.w*v1.w;
#pragma unroll
  for (int o = 32; o > 0; o >>= 1) s += __shfl_xor(s, o, 64);
  if (lane == 0) dst[row] = 1.0f / fmaxf(sqrtf(s), 1e-8f);
}

// ---------------------------------------------------------------------------
// Kernel 2: cost GEMM -> BLOCK-DIAG layout, PRE-SCALED by ig2 = log2e/gv:
//   costB = (1 - dot*rn) * ig2.   Each thread's 4x4 micro-tile is one block.
// ---------------------------------------------------------------------------
__global__ void __launch_bounds__(256) cost_gemm(const float* __restrict__ x,
                                                 const float* __restrict__ y,
                                                 const float* __restrict__ rnx,
                                                 const float* __restrict__ rny,
                                                 const float* __restrict__ gamma,
                                                 float* __restrict__ costB) {
  int b = blockIdx.z, mt = blockIdx.y, nt = blockIdx.x;
  int m0 = mt * 64, n0 = nt * 64;
  __shared__ float Xs[16][68];
  __shared__ float Ys[16][68];
  int tid = threadIdx.x;
  int row = tid >> 2, cq = tid & 3;
  int tx = tid & 15, ty = tid >> 4;
  const float* xb = x + ((size_t)b * 256 + m0) * 512;
  const float* yb = y + ((size_t)b * 256 + n0) * 512;
  float acc[4][4] = {};
  for (int k0 = 0; k0 < 512; k0 += 16) {
    float4 xv = *(const float4*)(xb + (size_t)row * 512 + k0 + cq * 4);
    float4 yv = *(const float4*)(yb + (size_t)row * 512 + k0 + cq * 4);
    __syncthreads();
    Xs[cq*4+0][row] = xv.x; Xs[cq*4+1][row] = xv.y;
    Xs[cq*4+2][row] = xv.z; Xs[cq*4+3][row] = xv.w;
    Ys[cq*4+0][row] = yv.x; Ys[cq*4+1][row] = yv.y;
    Ys[cq*4+2][row] = yv.z; Ys[cq*4+3][row] = yv.w;
    __syncthreads();
#pragma unroll
    for (int kk = 0; kk < 16; ++kk) {
      float4 av = *(const float4*)(&Xs[kk][ty * 4]);
      float4 bv = *(const float4*)(&Ys[kk][tx * 4]);
      float ar[4] = {av.x, av.y, av.z, av.w};
      float br[4] = {bv.x, bv.y, bv.z, bv.w};
#pragma unroll
      for (int r = 0; r < 4; ++r)
#pragma unroll
        for (int c = 0; c < 4; ++c)
          acc[r][c] += ar[r] * br[c];
    }
  }
  float gv = fmaxf(fabsf(gamma[0]), 1e-4f);
  float ig2 = 1.4426950408889634f / gv;
  float rx[4], ry[4];
#pragma unroll
  for (int r = 0; r < 4; ++r) rx[r] = rnx[b * 256 + m0 + ty * 4 + r];
#pragma unroll
  for (int c = 0; c < 4; ++c) ry[c] = rny[b * 256 + n0 + tx * 4 + c];
  int I = mt * 16 + ty, J = nt * 16 + tx;
  float* bp = costB + (size_t)b * BSTRIDE + ((size_t)(I + J) * 64 + I) * 16;
#pragma unroll
  for (int c = 0; c < 4; ++c) {
    float4 st = {(1.0f - acc[0][c] * rx[0] * ry[c]) * ig2,
                 (1.0f - acc[1][c] * rx[1] * ry[c]) * ig2,
                 (1.0f - acc[2][c] * rx[2] * ry[c]) * ig2,
                 (1.0f - acc[3][c] * rx[3] * ry[c]) * ig2};
    *(float4*)(bp + c * 4) = st;
  }
}

// ---------------------------------------------------------------------------
// Kernel 3: forward soft-DTW, block-diag, NB batches interleaved per wave.
// Lane l owns row-strip I=l of each batch; at slot s processes block (l,s-l)
// of all NB batches -- independent chains fill each other's latency stalls.
// q = R*log2e/gv; cost is pre-scaled so the cell update is an add.
// ---------------------------------------------------------------------------
__device__ __forceinline__ void fwd_slot(int s, int l, const float cc[NB][16],
                                         float pc[NB][4], float bot[NB][4],
                                         float carry[NB], float* __restrict__ qb0) {
  int g = s - l;
  bool act = (g >= 0) && (g <= 63);
  float up[NB][4], dg0[NB];
#pragma unroll
  for (int u = 0; u < NB; ++u) {
    up[u][0] = __shfl_up(bot[u][0], 1);
    up[u][1] = __shfl_up(bot[u][1], 1);
    up[u][2] = __shfl_up(bot[u][2], 1);
    up[u][3] = __shfl_up(bot[u][3], 1);
    dg0[u] = carry[u];
    carry[u] = up[u][3];
    if (l == 0) {
      up[u][0] = up[u][1] = up[u][2] = up[u][3] = INFV;
      dg0[u] = (g == 0) ? 0.0f : INFV;
    }
  }
  float left[NB][4], outv[NB][16], pu[NB], pd[NB];
#pragma unroll
  for (int u = 0; u < NB; ++u)
#pragma unroll
    for (int k = 0; k < 4; ++k) left[u][k] = pc[u][k];
#pragma unroll
  for (int j = 0; j < 4; ++j) {
#pragma unroll
    for (int u = 0; u < NB; ++u) {
      pu[u] = up[u][j];
      pd[u] = (j == 0) ? dg0[u] : up[u][j - 1];
    }
#pragma unroll
    for (int k = 0; k < 4; ++k) {
#pragma unroll
      for (int u = 0; u < NB; ++u) {      // adjacent independent chains
        float a = pu[u], bb = left[u][k], c = pd[u];
        float mn = fminf(a, fminf(bb, c));
        float s3 = EXP2F(mn - a) + EXP2F(mn - bb) + EXP2F(mn - c);
        float v = cc[u][j * 4 + k] + (mn - LOG2F(s3));
        pd[u] = bb; pu[u] = v;
        outv[u][j * 4 + k] = v;
        left[u][k] = v;
      }
    }
  }
  if (act) {
#pragma unroll
    for (int u = 0; u < NB; ++u) {
#pragma unroll
      for (int k = 0; k < 4; ++k) pc[u][k] = left[u][k];
#pragma unroll
      for (int j = 0; j < 4; ++j) bot[u][j] = outv[u][j * 4 + 3];
      float* bp = qb0 + (size_t)u * BSTRIDE + (size_t)s * CHUNK + l * 16;
#pragma unroll
      for (int j = 0; j < 4; ++j) {
        float4 st = {outv[u][4*j+0], outv[u][4*j+1], outv[u][4*j+2], outv[u][4*j+3]};
        *(float4*)(bp + 4 * j) = st;
      }
    }
  }
}

__global__ void __launch_bounds__(64, 1) fwd_kernel(const float* __restrict__ costB,
                                                    const float* __restrict__ gamma,
                                                    float* __restrict__ qBuf,
                                                    float* __restrict__ dist_out) {
  int p = blockIdx.x, l = threadIdx.x;
  int b0 = p * NB;
  float gv = fmaxf(fabsf(gamma[0]), 1e-4f);
  float gl = gv * 0.6931471805599453f;   // R = q * gl
  const float* cb = costB + (size_t)b0 * BSTRIDE + l * 16;
  float* qb0 = qBuf + (size_t)b0 * BSTRIDE;
  float pc[NB][4], bot[NB][4], carry[NB];
#pragma unroll
  for (int u = 0; u < NB; ++u) {
    carry[u] = INFV;
#pragma unroll
    for (int k = 0; k < 4; ++k) { pc[u][k] = INFV; bot[u][k] = INFV; }
  }
  float C0[NB][16], C1[NB][16], C2[NB][16];
  auto loadC = [&](int s, float (*buf)[16]) {
    int sc = min(s, 127);
#pragma unroll
    for (int u = 0; u < NB; ++u)
      ld16(buf[u], cb + (size_t)u * BSTRIDE + (size_t)sc * CHUNK);
  };
  loadC(0, C0); loadC(1, C1); loadC(2, C2);
  for (int it = 0; it < 43; ++it) {   // 129 slots; last live slot = 126
    int s = it * 3;
    fwd_slot(s + 0, l, C0, pc, bot, carry, qb0);
    loadC(s + 3, C0);
    fwd_slot(s + 1, l, C1, pc, bot, carry, qb0);
    loadC(s + 4, C1);
    fwd_slot(s + 2, l, C2, pc, bot, carry, qb0);
    loadC(s + 5, C2);
  }
  if (l == 63) {
#pragma unroll
    for (int u = 0; u < NB; ++u) dist_out[b0 + u] = bot[u][3] * gl;
  }
}

// ---------------------------------------------------------------------------
// Kernel 3.5: backward weights, one thread per target block (I,J).
// cost is pre-scaled, so exponent = (q_x - csc_x) - q_c.  Masking folded in.
// ---------------------------------------------------------------------------
__global__ void __launch_bounds__(256) weights_kernel(const float* __restrict__ qBuf,
                                                      const float* __restrict__ costB,
                                                      float* __restrict__ WD,
                                                      float* __restrict__ WN,
                                                      float* __restrict__ WR) {
  int b = blockIdx.y;
  int tb = blockIdx.x * 256 + threadIdx.x;   // 0..4095
  int J = tb & 63, I = tb >> 6;
  const float LOG2E = 1.4426950408889634f;
  const float CL = 50.0f * LOG2E;
  const float* qb = qBuf  + (size_t)b * BSTRIDE;
  const float* cb = costB + (size_t)b * BSTRIDE;
  auto bo = [](int i, int j) { return ((size_t)(i + j) * 64 + i) * 16; };
  int Ic = min(I + 1, 63), Jc = min(J + 1, 63);
  float qA[16], qBk[16], qCk[16], qDk[16], cBk[16], cCk[16], cDk[16];
  ld16(qA,  qb + bo(I, J));
  ld16(qBk, qb + bo(Ic, J));
  ld16(qCk, qb + bo(I, Jc));
  ld16(qDk, qb + bo(Ic, Jc));
  float cA[16];
  ld16(cA,  cb + bo(I, J));
  ld16(cBk, cb + bo(Ic, J));
  ld16(cCk, cb + bo(I, Jc));
  ld16(cDk, cb + bo(Ic, Jc));
  float od[16], on[16], orr[16];
#pragma unroll
  for (int j = 0; j < 4; ++j) {
#pragma unroll
    for (int k = 0; k < 4; ++k) {
      float q_c = qA[j*4+k];
      float q_n = (k < 3) ? qA[j*4+k+1] : qBk[j*4+0];
      float q_r = (j < 3) ? qA[(j+1)*4+k] : qCk[k];
      float q_d = (k < 3) ? ((j < 3) ? qA[(j+1)*4+k+1] : qCk[k+1])
                          : ((j < 3) ? qBk[(j+1)*4+0] : qDk[0]);
      float c_n = (k < 3) ? cA[j*4+k+1] : cBk[j*4+0];
      float c_r = (j < 3) ? cA[(j+1)*4+k] : cCk[k];
      float c_d = (k < 3) ? ((j < 3) ? cA[(j+1)*4+k+1] : cCk[k+1])
                          : ((j < 3) ? cBk[(j+1)*4+0] : cDk[0]);
      float ad = fminf(fmaxf((q_d - c_d) - q_c, -CL), CL);
      float an = fminf(fmaxf((q_n - c_n) - q_c, -CL), CL);
      float ar = fminf(fmaxf((q_r - c_r) - q_c, -CL), CL);
      bool rm = !(I == 63 && k == 3);   // r < 255
      bool cm = !(J == 63 && j == 3);   // c < 255
      od[j*4+k]  = (rm && cm) ? EXP2F(ad) : 0.0f;
      on[j*4+k]  = rm ? EXP2F(an) : 0.0f;
      orr[j*4+k] = cm ? EXP2F(ar) : 0.0f;
    }
  }
  size_t o = (size_t)b * BSTRIDE + bo(I, J);
#pragma unroll
  for (int j = 0; j < 4; ++j) {
    *(float4*)(WD + o + 4*j) = *(float4*)(od + 4*j);
    *(float4*)(WN + o + 4*j) = *(float4*)(on + 4*j);
    *(float4*)(WR + o + 4*j) = *(float4*)(orr + 4*j);
  }
}

// ---------------------------------------------------------------------------
// Kernel 4: backward recurrence, block-diag, NB batches per wave.
//   E[r][c] = E[r+1][c+1]*wd + E[r+1][c]*wn + E[r][c+1]*wr,  E[255][255]=1.
// Lane l owns strip I=l; slot u processes block (l, 126-u-l) of all batches.
// ---------------------------------------------------------------------------
__device__ __forceinline__ void bwd_slot(int u, int l,
    const float wd[NB][16], const float wn[NB][16], const float wr[NB][16],
    float right[NB][4], float top[NB][4], float carry[NB],
    float* __restrict__ EB0) {
  int J = 126 - u - l;
  bool act = (J >= 0) && (J <= 63);
  float dt[NB][4], dgc[NB];
#pragma unroll
  for (int v = 0; v < NB; ++v) {
    dt[v][0] = __shfl_down(top[v][0], 1);
    dt[v][1] = __shfl_down(top[v][1], 1);
    dt[v][2] = __shfl_down(top[v][2], 1);
    dt[v][3] = __shfl_down(top[v][3], 1);
    dgc[v] = carry[v];
    carry[v] = dt[v][0];
    if (l == 63) { dt[v][0] = dt[v][1] = dt[v][2] = dt[v][3] = 0.0f; dgc[v] = 0.0f; }
  }
  float colR[NB][4], outv[NB][16], dn[NB], drt[NB];
#pragma unroll
  for (int v = 0; v < NB; ++v)
#pragma unroll
    for (int k = 0; k < 4; ++k) colR[v][k] = right[v][k];
#pragma unroll
  for (int j = 3; j >= 0; --j) {
#pragma unroll
    for (int v = 0; v < NB; ++v) {
      dn[v]  = dt[v][j];
      drt[v] = (j == 3) ? dgc[v] : dt[v][j + 1];
    }
#pragma unroll
    for (int k = 3; k >= 0; --k) {
#pragma unroll
      for (int v = 0; v < NB; ++v) {
        float rt = colR[v][k];
        float val = drt[v] * wd[v][j*4+k] + dn[v] * wn[v][j*4+k] + rt * wr[v][j*4+k];
        if (l == 63 && J == 63 && j == 3 && k == 3) val = 1.0f;
        drt[v] = rt; dn[v] = val;
        outv[v][j*4+k] = val;
      }
    }
#pragma unroll
    for (int v = 0; v < NB; ++v)
#pragma unroll
      for (int k = 0; k < 4; ++k) colR[v][k] = outv[v][j*4+k];
  }
  if (act) {
#pragma unroll
    for (int v = 0; v < NB; ++v) {
#pragma unroll
      for (int k = 0; k < 4; ++k) right[v][k] = colR[v][k];
#pragma unroll
      for (int j = 0; j < 4; ++j) top[v][j] = outv[v][j*4+0];
      float* bp = EB0 + (size_t)v * BSTRIDE + (size_t)(126 - u) * CHUNK + l * 16;
#pragma unroll
      for (int j = 0; j < 4; ++j) {
        float4 st = {outv[v][4*j+0], outv[v][4*j+1], outv[v][4*j+2], outv[v][4*j+3]};
        *(float4*)(bp + 4 * j) = st;
      }
    }
  }
}

__global__ void __launch_bounds__(64, 1) bwd_kernel(const float* __restrict__ WD,
                                                    const float* __restrict__ WN,
                                                    const float* __restrict__ WR,
                                                    float* __restrict__ EB) {
  int p = blockIdx.x, l = threadIdx.x;
  int b0 = p * NB;
  const float* wdb = WD + (size_t)b0 * BSTRIDE + l * 16;
  const float* wnb = WN + (size_t)b0 * BSTRIDE + l * 16;
  const float* wrb = WR + (size_t)b0 * BSTRIDE + l * 16;
  float* EB0 = EB + (size_t)b0 * BSTRIDE;
  float right[NB][4] = {}, top[NB][4] = {}, carry[NB] = {};
  float Da[NB][16], Na[NB][16], Ra[NB][16];
  float Db[NB][16], Nb[NB][16], Rb[NB][16];
  auto loadW = [&](int u, float (*D)[16], float (*N)[16], float (*R)[16]) {
    size_t off = (size_t)max(126 - u, 0) * CHUNK;
#pragma unroll
    for (int v = 0; v < NB; ++v) {
      ld16(D[v], wdb + (size_t)v * BSTRIDE + off);
      ld16(N[v], wnb + (size_t)v * BSTRIDE + off);
      ld16(R[v], wrb + (size_t)v * BSTRIDE + off);
    }
  };
  loadW(0, Da, Na, Ra);
  loadW(1, Db, Nb, Rb);
  for (int it = 0; it < 64; ++it) {   // 128 slots; last live slot = 126
    int u = it * 2;
    bwd_slot(u + 0, l, Da, Na, Ra, right, top, carry, EB0);
    loadW(u + 2, Da, Na, Ra);
    bwd_slot(u + 1, l, Db, Nb, Rb, right, top, carry, EB0);
    loadW(u + 3, Db, Nb, Rb);
  }
}

// ---------------------------------------------------------------------------
// Kernel 5: block-diag -> row-major.  out[b][4I+k][4J+j] = EB block (I,J)[j*4+k].
// ---------------------------------------------------------------------------
__global__ void __launch_bounds__(256) transpose_kernel(const float* __restrict__ EB,
                                                        float* __restrict__ out) {
  int b = blockIdx.z, mt = blockIdx.y, nt = blockIdx.x;
  __shared__ float T[16 * 16 * 17];
  const float* Eb = EB + (size_t)b * BSTRIDE;
  int t = threadIdx.x;
  int Ii = mt * 16 + (t >> 4), Jj = nt * 16 + (t & 15);
  const float* bp = Eb + ((size_t)(Ii + Jj) * 64 + Ii) * 16;
  float* dst = &T[((t >> 4) * 16 + (t & 15)) * 17];
  float tmp[16];
  ld16(tmp, bp);
#pragma unroll
  for (int q = 0; q < 16; ++q) dst[q] = tmp[q];
  __syncthreads();
  float* ob = out + ((size_t)b * 256 + mt * 64) * 256 + nt * 64;
#pragma unroll
  for (int it = 0; it < 16; ++it) {
    int lin = it * 256 + t;
    int mm = lin >> 6, nn = lin & 63;
    int Ib = mm >> 2, k = mm & 3, Jb = nn >> 2, j = nn & 3;
    ob[(size_t)mm * 256 + nn] = T[(Ib * 16 + Jb) * 17 + j * 4 + k];
  }
}

// ---------------------------------------------------------------------------
// Workspace (floats), ~21.0 MB:
//   rnx @ 0 (2048) | rny @ 2048 (2048)
//   costB @ 4096 (8*131072, pre-scaled by ig2) [aliased as EB by bwd]
//   qB | WD | WN | WR  (each 8*131072)
// d_out: alignment [0 .. 524287], distance [524288 .. 524295].
// ---------------------------------------------------------------------------
extern "C" void kernel_launch(void* const* d_in, const int* in_sizes, int n_in,
                              void* d_out, int out_size, void* d_ws, size_t ws_size,
                              hipStream_t stream) {
  const float* x = (const float*)d_in[0];
  const float* y = (const float*)d_in[1];
  const float* gamma = (const float*)d_in[2];
  float* out = (float*)d_out;
  float* ws = (float*)d_ws;

  const size_t MAT = (size_t)8 * BSTRIDE;
  float* rnx   = ws;
  float* rny   = ws + 2048;
  float* costB = ws + 4096;
  float* qB    = costB + MAT;
  float* WDp   = qB    + MAT;
  float* WNp   = WDp   + MAT;
  float* WRp   = WNp   + MAT;
  float* EB    = costB;   // alias: costB dead after weights_kernel

  norms_kernel<<<1024, 256, 0, stream>>>(x, y, rnx, rny);
  cost_gemm<<<dim3(4, 4, 8), 256, 0, stream>>>(x, y, rnx, rny, gamma, costB);
  fwd_kernel<<<8 / NB, 64, 0, stream>>>(costB, gamma, qB, out + 524288);
  weights_kernel<<<dim3(16, 8), 256, 0, stream>>>(qB, costB, WDp, WNp, WRp);
  bwd_kernel<<<8 / NB, 64, 0, stream>>>(WDp, WNp, WRp, EB);
  transpose_kernel<<<dim3(4, 4, 8), 256, 0, stream>>>(EB, out);
}